// Round 14
// baseline (348.324 us; speedup 1.0000x reference)
//
#include <hip/hip_runtime.h>
#include <hip/hip_bf16.h>

// DGCF forward, MI355X. f32 in/out.
// R11-R22: padded-bucket CSR build, fused walk+scores+softmax+D, bf16 tables,
// dot2bf, pre-scaled G=x*d, merged per-edge record svA = {sv bf16 | A f16}.
// R24: 8 lanes per edge slot (one uint4/lane) — request-rate fix, 59 us/iter.
// R25: (a) k_init folded into k_bucket (deg in LDS -> d0; streaming embed
// init hides under the scatter's latency; k_init dispatch + d4a die);
// (b) it3 out is WRITE-ONLY: out = (bf16(init via ego_a) + fn1 + fn3)/3
// — kills init's 25.6 MB out-write and it3's 25.6 MB out-read.
#define NUSER 50000
#define NITEM 50000
#define NN    100000          // NUSER+NITEM
#define NNZ_  1000000
#define DIM_  64
#define NBLK  391             // ceil_div(NN,256) == bucket count
#define EPB   2560            // edges per scatter block (391*2560 >= NNZ)
#define BINC  4096            // per-bucket window capacity (mean 2560, +30 sigma)
#define NPAD  (NBLK * BINC)   // padded edge-index space (1,601,536)

#define FL_SVC    1   // walk weights uniform (it0; constant cancels in norm)
#define FL_SC     2   // fused scores: dot(fn, te[tail]) -> A -> softmax -> svA
#define FL_NEXT   8   // write ego_next(raw) / te_next / Gnext(from regs)
#define FL_FIN    16  // out = (Xa_row + X_row + fn) / 3  (write-only out)
#define FL_ACONST 32  // scores: A_old == 1 (skip record load if also FL_SVC)
#define FL_GN     128 // build Gnext = X_row * d  (X loaded, d from scores)

static inline int ceil_div(int a, int b) { return (a + b - 1) / b; }

static __device__ inline float bf2f(unsigned short u) {
    return __uint_as_float(((unsigned int)u) << 16);
}
static __device__ inline float blo(unsigned int u) {
    return __uint_as_float(u << 16);
}
static __device__ inline float bhi(unsigned int u) {
    return __uint_as_float(u & 0xffff0000u);
}
static __device__ inline unsigned short f2bf(float f) {
    unsigned int x = __float_as_uint(f);
    x += 0x7fffu + ((x >> 16) & 1u);
    return (unsigned short)(x >> 16);
}
static __device__ inline unsigned short f2h(float f) {
    _Float16 h = (_Float16)f;
    return __builtin_bit_cast(unsigned short, h);
}
static __device__ inline float h2f(unsigned short u) {
    return (float)__builtin_bit_cast(_Float16, u);
}

// packed bf16x2 dot: c += a.lo*b.lo + a.hi*b.hi (hw v_dot2_f32_bf16 if present)
#if __has_builtin(__builtin_amdgcn_fdot2_f32_bf16)
typedef __bf16 bf16x2_t __attribute__((ext_vector_type(2)));
static __device__ inline float dot2bf(unsigned int a, unsigned int b, float c) {
    return __builtin_amdgcn_fdot2_f32_bf16(__builtin_bit_cast(bf16x2_t, a),
                                           __builtin_bit_cast(bf16x2_t, b), c, false);
}
#else
static __device__ inline float dot2bf(unsigned int a, unsigned int b, float c) {
    return c + blo(a) * blo(b) + bhi(a) * bhi(b);
}
#endif

// ---- padded-bucket CSR build (once per launch) ----
__global__ void k_binscat(const int* __restrict__ head, const int* __restrict__ tail,
                          int* __restrict__ cursor, int* __restrict__ bin) {
    __shared__ int cnt[NBLK];
    __shared__ int chunk[NBLK];
    int tid = threadIdx.x;
    for (int i = tid; i < NBLK; i += 256) cnt[i] = 0;
    __syncthreads();
    int e0 = blockIdx.x * EPB;
    int e1 = min(e0 + EPB, NNZ_);
    for (int e = e0 + tid; e < e1; e += 256)
        atomicAdd(&cnt[head[e] >> 8], 1);
    __syncthreads();
    for (int i = tid; i < NBLK; i += 256) {
        chunk[i] = cnt[i] ? (i * BINC + atomicAdd(&cursor[i], cnt[i])) : 0;
        cnt[i] = 0;   // reuse as local cursor
    }
    __syncthreads();
    for (int e = e0 + tid; e < e1; e += 256) {
        int h = head[e], t = tail[e];
        int b = h >> 8;
        int off = atomicAdd(&cnt[b], 1);
        bin[chunk[b] + off] = t | ((h & 255) << 20);   // t < 2^17, hl < 2^8
    }
}

// per-bucket: LDS deg hist -> scan -> row_se + tail scatter; then FUSED
// embedding init for this bucket's 256 nodes (ego raw, te, G0 = ego*d0).
__global__ void k_bucket(const int* __restrict__ bin, const int* __restrict__ cursor,
                         const float* __restrict__ eu, const float* __restrict__ ei,
                         int2* __restrict__ row_se, int* __restrict__ csr_tail,
                         unsigned short* __restrict__ ego, unsigned short* __restrict__ te,
                         unsigned short* __restrict__ G0) {
    __shared__ int deg[256];
    __shared__ int sh[256];
    __shared__ int cur[256];
    int tid = threadIdx.x;
    int b = blockIdx.x;
    int n0 = b << 8;
    int e0 = b * BINC, e1 = e0 + cursor[b];
    deg[tid] = 0;
    __syncthreads();
    for (int e = e0 + tid; e < e1; e += 256)
        atomicAdd(&deg[bin[e] >> 20], 1);
    __syncthreads();
    int myDeg = deg[tid];
    sh[tid] = myDeg;
    __syncthreads();
    for (int off = 1; off < 256; off <<= 1) {
        int u = 0;
        if (tid >= off) u = sh[tid - off];
        __syncthreads();
        sh[tid] += u;
        __syncthreads();
    }
    int loff = sh[tid] - myDeg;   // exclusive local offset
    int start = b * BINC + loff;  // csr window shares the BINC stride
    int n = n0 + tid;
    if (n < NN)
        row_se[n] = make_int2(start, start + myDeg);
    cur[tid] = start;
    __syncthreads();
    for (int e = e0 + tid; e < e1; e += 256) {
        int p = bin[e];
        int pos = atomicAdd(&cur[p >> 20], 1);
        csr_tail[pos] = p & 0xFFFFF;
    }
    // ---- fused embedding init (deg[] stable since hist phase) ----
    int base_el = n0 * 64;
    int lim = min(256 * 64, NN * DIM_ - base_el);
    for (int idx = tid; idx < lim; idx += 256) {
        int i = base_el + idx;
        float v = (i < NUSER * DIM_) ? eu[i] : ei[i - NUSER * DIM_];
        ego[i] = f2bf(v);
        int dg = deg[idx >> 6];
        float dd = (dg > 0) ? 2.0f / sqrtf((float)dg) : 0.0f;
        G0[i] = f2bf(v * dd);
        float s = v * v;
        s += __shfl_xor(s, 1); s += __shfl_xor(s, 2);
        s += __shfl_xor(s, 4); s += __shfl_xor(s, 8);
        float nrm = v / fmaxf(sqrtf(s), 1e-12f);
        float ex = __expf(2.0f * nrm);
        te[i] = f2bf((ex - 1.0f) / (ex + 1.0f));
    }
}

#define QRED(a) { a += __shfl_xor(a, 8); a += __shfl_xor(a, 16); a += __shfl_xor(a, 32); }

// ---- fused walk + scores body ----
// lane = 8q + l8: q = edge slot (0..7), l8 = dim octet (dims 8*l8..8*l8+7,
// all within factor f2 = l8>>1). One uint4 (16 B) load covers a lane's dims.
// NJ = chunk0 depth in 8-edge groups (1 or 2); NJ==2 arm also handles deg>16.
template<int FLAGS, int NJ>
static __device__ __forceinline__ void iter_body(
    int n, int lane, int q, int l8, int f2, int r0, int r1,
    unsigned int* __restrict__ svA,
    const unsigned short* __restrict__ G,
    const unsigned short* __restrict__ te,
    const int* __restrict__ csr_tail,
    float* __restrict__ out,
    const unsigned short* __restrict__ X,   // raw row source (GN / FIN term 2)
    const unsigned short* __restrict__ Xa,  // FIN term 1 (raw init)
    unsigned short* __restrict__ Gn,
    unsigned short* __restrict__ egon, unsigned short* __restrict__ ten)
{
    constexpr bool needRec = !(FLAGS & FL_SVC) || ((FLAGS & FL_SC) && !(FLAGS & FL_ACONST));
    float a0 = 0.f, a1 = 0.f, a2 = 0.f, a3 = 0.f;
    float a4 = 0.f, a5 = 0.f, a6 = 0.f, a7 = 0.f;

    // ---- chunk 0: edges r0 + q + 8j, j=0..NJ-1 (te cached for scores) ----
    int ct[NJ]; float cw[NJ]; unsigned int cr[NJ]; uint4 cv[NJ];
#pragma unroll
    for (int j = 0; j < NJ; ++j) {
        int i = r0 + q + 8 * j;
        bool v = (i < r1);
        int ic = v ? i : r0;
        int t = csr_tail[ic];
        ct[j] = v ? t : 0;            // padding holes are uninitialized
        if (needRec) cr[j] = svA[ic * 4 + f2];
        float w;
        if (FLAGS & FL_SVC) w = 1.0f;
        else w = bf2f((unsigned short)(cr[j] & 0xffffu));
        cw[j] = v ? w : 0.f;
    }
#pragma unroll
    for (int j = 0; j < NJ; ++j) {
        if (FLAGS & FL_SC)
            cv[j] = *(const uint4*)(te + ct[j] * 64 + 8 * l8);
    }
#pragma unroll
    for (int j = 0; j < NJ; ++j) {
        uint4 gu = *(const uint4*)(G + ct[j] * 64 + 8 * l8);
        float w = cw[j];
        a0 += w * blo(gu.x); a1 += w * bhi(gu.x);
        a2 += w * blo(gu.y); a3 += w * bhi(gu.y);
        a4 += w * blo(gu.z); a5 += w * bhi(gu.z);
        a6 += w * blo(gu.w); a7 += w * bhi(gu.w);
    }

    // ---- remainder (deg > 16), NJ==2 arm only: 8 edges per step ----
    if (NJ == 2) {
        for (int base = r0 + 16; base < r1; base += 8) {
            int i = base + q;
            bool v = (i < r1);
            int ic = v ? i : r0;
            int t = csr_tail[ic];
            t = v ? t : 0;
            float w;
            if (FLAGS & FL_SVC) w = 1.0f;
            else w = bf2f((unsigned short)(svA[ic * 4 + f2] & 0xffffu));
            w = v ? w : 0.f;
            uint4 gu = *(const uint4*)(G + t * 64 + 8 * l8);
            a0 += w * blo(gu.x); a1 += w * bhi(gu.x);
            a2 += w * blo(gu.y); a3 += w * bhi(gu.y);
            a4 += w * blo(gu.z); a5 += w * bhi(gu.z);
            a6 += w * blo(gu.w); a7 += w * bhi(gu.w);
        }
    }

    // reduce over the 8 edge slots (lane bits 3,4,5)
    QRED(a0) QRED(a1) QRED(a2) QRED(a3)
    QRED(a4) QRED(a5) QRED(a6) QRED(a7)

    // l2 norm over the 16-dim factor chunk (pair l8^1 holds the other 8 dims)
    float s = a0 * a0 + a1 * a1 + a2 * a2 + a3 * a3
            + a4 * a4 + a5 * a5 + a6 * a6 + a7 * a7;
    s += __shfl_xor(s, 1);
    float inv = 1.0f / fmaxf(sqrtf(s), 1e-12f);
    float f0 = a0 * inv, f1 = a1 * inv, f2v = a2 * inv, f3 = a3 * inv;
    float f4 = a4 * inv, f5 = a5 * inv, f6 = a6 * inv, f7 = a7 * inv;

    // epilogue dim ownership: lane (q,l8) writes dim k = 8*l8 + q (bijective)
    int k = 8 * l8 + q;
    float y = 0.f;
    if (FLAGS & (FL_NEXT | FL_FIN)) {
        y = (q & 4) ? ((q & 2) ? ((q & 1) ? f7 : f6) : ((q & 1) ? f5 : f4))
                    : ((q & 2) ? ((q & 1) ? f3 : f2v) : ((q & 1) ? f1 : f0));
        int base = n * 64 + k;
        if (FLAGS & FL_FIN) {
            // write-only out: init term (Xa) and fn1 term (X) both raw bf16
            out[base] = (bf2f(Xa[base]) + bf2f(X[base]) + y) * (1.0f / 3.0f);
        }
        if (FLAGS & FL_NEXT) {
            egon[base] = f2bf(y);
            float e2 = __expf(2.0f * y);
            ten[base] = f2bf((e2 - 1.0f) / (e2 + 1.0f));
        }
    }

    float accs = 0.f;   // rowsum of svals for factor f2 (per q-subset, then QRED)
    if (FLAGS & FL_SC) {
        // pack fn: 4 bf16x2 words covering the lane's 8 dims
        unsigned int p0 = ((unsigned int)f2bf(f1) << 16) | f2bf(f0);
        unsigned int p1 = ((unsigned int)f2bf(f3) << 16) | f2bf(f2v);
        unsigned int p2 = ((unsigned int)f2bf(f5) << 16) | f2bf(f4);
        unsigned int p3 = ((unsigned int)f2bf(f7) << 16) | f2bf(f6);
        // cached chunk 0: pure register compute
#pragma unroll
        for (int j = 0; j < NJ; ++j) {
            int i = r0 + q + 8 * j;
            bool v = (i < r1);
            float dot = dot2bf(cv[j].w, p3, dot2bf(cv[j].z, p2,
                        dot2bf(cv[j].y, p1, dot2bf(cv[j].x, p0, 0.0f))));
            dot += __shfl_xor(dot, 1);            // full 16-dim factor dot
            float a = (FLAGS & FL_ACONST) ? 1.0f : h2f((unsigned short)(cr[j] >> 16));
            a += dot;
            float ex = __expf(a);
            float sum = ex;
            sum += __shfl_xor(sum, 2); sum += __shfl_xor(sum, 4);  // over 4 factors
            float sv = ex / sum;
            if (v && (l8 & 1) == 0)
                svA[i * 4 + f2] = (unsigned int)f2bf(sv) | ((unsigned int)f2h(a) << 16);
            accs += v ? sv : 0.f;
        }
        // remainder chunks: re-gather tails/records -> te
        if (NJ == 2) {
            for (int base = r0 + 16; base < r1; base += 8) {
                int i = base + q;
                bool v = (i < r1);
                int ic = v ? i : r0;
                int t = csr_tail[ic];
                t = v ? t : 0;
                float aj = 1.0f;
                if (!(FLAGS & FL_ACONST))
                    aj = h2f((unsigned short)(svA[ic * 4 + f2] >> 16));
                uint4 tv = *(const uint4*)(te + t * 64 + 8 * l8);
                float dot = dot2bf(tv.w, p3, dot2bf(tv.z, p2,
                            dot2bf(tv.y, p1, dot2bf(tv.x, p0, 0.0f))));
                dot += __shfl_xor(dot, 1);
                float a = aj + dot;
                float ex = __expf(a);
                float sum = ex;
                sum += __shfl_xor(sum, 2); sum += __shfl_xor(sum, 4);
                float sv = ex / sum;
                if (v && (l8 & 1) == 0)
                    svA[i * 4 + f2] = (unsigned int)f2bf(sv) | ((unsigned int)f2h(a) << 16);
                accs += v ? sv : 0.f;
            }
        }
        QRED(accs)   // total rowsum for factor f2, replicated on all lanes
    }

    if (FLAGS & (FL_GN | FL_NEXT)) {
        // d for the OUTPUT dim's factor fo = k>>4; accs for factor g lives on
        // lane l8 = 2g (q = 0).
        int fo = k >> 4;
        float av = __shfl(accs, 2 * fo);
        float d = (av > 0.f) ? 1.0f / sqrtf(fmaxf(av, 1e-12f)) : 0.f;
        int base = n * 64 + k;
        float src = (FLAGS & FL_NEXT) ? y : bf2f(X[base]);
        Gn[base] = f2bf(src * d);
    }
}

// dispatcher: one wave per node; deg is wave-uniform (SGPR) -> scalar branch
template<int FLAGS>
__global__ void k_iter(unsigned int* __restrict__ svA,
                       const unsigned short* __restrict__ G,
                       const unsigned short* __restrict__ te,
                       const int2* __restrict__ row_se, const int* __restrict__ csr_tail,
                       float* __restrict__ out,
                       const unsigned short* __restrict__ X,
                       const unsigned short* __restrict__ Xa,
                       unsigned short* __restrict__ Gn,
                       unsigned short* __restrict__ egon, unsigned short* __restrict__ ten) {
    int n = (blockIdx.x * 256 + threadIdx.x) >> 6;
    if (n >= NN) return;
    int lane = threadIdx.x & 63;
    int q = lane >> 3;
    int l8 = lane & 7;
    int f2 = l8 >> 1;
    int2 se = row_se[n];
    int r0 = __builtin_amdgcn_readfirstlane(se.x);
    int r1 = __builtin_amdgcn_readfirstlane(se.y);
    if (r1 - r0 <= 8)
        iter_body<FLAGS, 1>(n, lane, q, l8, f2, r0, r1, svA, G, te,
                            csr_tail, out, X, Xa, Gn, egon, ten);
    else
        iter_body<FLAGS, 2>(n, lane, q, l8, f2, r0, r1, svA, G, te,
                            csr_tail, out, X, Xa, Gn, egon, ten);
}

extern "C" void kernel_launch(void* const* d_in, const int* in_sizes, int n_in,
                              void* d_out, int out_size, void* d_ws, size_t ws_size,
                              hipStream_t stream) {
    const float* eu = (const float*)d_in[0];
    const float* ei = (const float*)d_in[1];
    const int* head = (const int*)d_in[2];
    const int* tail = (const int*)d_in[3];
    float* out = (float*)d_out;   // WRITE-ONLY, filled at it3 (FL_FIN)

    // workspace layout — ~110 MB (16B-aligned first).
    // svA = merged per-edge record (NPAD*4 uints). bin (6.4 MB) aliases svA
    // (bin dead after k_bucket; svA first written in it0's scores phase).
    unsigned int* svA = (unsigned int*)d_ws;                // 25.6 MB (NPAD*4)
    unsigned short* ego_a = (unsigned short*)(svA + (size_t)NPAD * 4);  // 12.8 MB (raw init)
    unsigned short* te_a  = ego_a + (size_t)NN * DIM_;      // 12.8 MB
    unsigned short* ego_b = te_a + (size_t)NN * DIM_;       // 12.8 MB (raw fn1)
    unsigned short* te_b  = ego_b + (size_t)NN * DIM_;      // 12.8 MB
    unsigned short* Ga    = te_b + (size_t)NN * DIM_;       // 12.8 MB
    unsigned short* Gb    = Ga + (size_t)NN * DIM_;         // 12.8 MB
    int* csr_tail = (int*)(Gb + (size_t)NN * DIM_);         // 6.4 MB (NPAD)
    int2* row_se = (int2*)(csr_tail + (size_t)NPAD);        // 0.8 MB
    int* cursor = (int*)(row_se + NN);                      // NBLK
    int* bin = (int*)svA;                                   // 6.4 MB alias

    const int wave_blocks = ceil_div(NN * 64, 256);        // 25000

    // padded-bucket CSR build; k_bucket also does the fused embedding init
    // (ego_a raw, te_a, G0 = ego_a*d0 -> Ga) using deg from its LDS hist.
    hipMemsetAsync(cursor, 0, NBLK * sizeof(int), stream);
    k_binscat<<<NBLK, 256, 0, stream>>>(head, tail, cursor, bin);
    k_bucket<<<NBLK, 256, 0, stream>>>(bin, cursor, eu, ei, row_se, csr_tail,
                                       ego_a, te_a, Ga);

    // it0: walk Ga (uniform weights cancel in norm); scores vs te_a:
    // A1 = 1 + s0, svals_1 -> svA (packed); epilogue G1 = ego_a*d1 -> Gb.
    k_iter<FL_SVC | FL_SC | FL_ACONST | FL_GN><<<wave_blocks, 256, 0, stream>>>(
        svA, Ga, te_a, row_se, csr_tail, out, ego_a, ego_a, Gb, ego_b, te_b);

    // it1: walk Gb with svals_1; fn1 -> ego_b(raw) + te_b; scores vs te_a:
    // A2 = A1 + s1, svals_2 -> svA; epilogue G2 = fn1*d2 -> Ga.
    k_iter<FL_SC | FL_NEXT><<<wave_blocks, 256, 0, stream>>>(
        svA, Gb, te_a, row_se, csr_tail, out, ego_a, ego_a, Ga, ego_b, te_b);

    // it2: walk Ga with svals_2; scores vs te_b: A3 = A2 + s2, svals_3 -> svA;
    // epilogue G3 = ego_b*d3 -> Gb.
    k_iter<FL_SC | FL_GN><<<wave_blocks, 256, 0, stream>>>(
        svA, Ga, te_b, row_se, csr_tail, out, ego_b, ego_a, Gb, ego_b, te_b);

    // it3: walk Gb with svals_3; no scores; out = (init(ego_a) + fn1(ego_b)
    // + fn3)/3 — out is write-only.
    k_iter<FL_FIN><<<wave_blocks, 256, 0, stream>>>(
        svA, Gb, te_b, row_se, csr_tail, out, ego_b, ego_a, Ga, ego_b, te_b);
}